// Round 16
// baseline (115.203 us; speedup 1.0000x reference)
//
#include <hip/hip_runtime.h>

// Fully-fused cascaded-biquad IIR (DF2T) via linear state-space chunking.
// R16 = R15 with LDS total EXACTLY 64KiB (the 2-blocks/CU cliff: 65536 ->
// 39% occupancy, 67584 -> 21%; R13/R14/R15 triangulation).
//   - Msh[7][64] + Bnd[8][8] ALIAS wave 0's arena region (idle between
//     P1 end and P4 start); squarings kept in registers until then.
//   - waves 1..7 prefetch their P4 HT0 right after barrier #1; raw
//     s_barriers with lgkm-only drains keep those gll loads in flight
//     across the scan. Wave 0 stages HT0 after barrier #3.
//   - scan math = R15 (numerically verified): in-wave Kogge-Stone via
//     __shfl, cross-wave Bnd fold, z = M^lane * P binary-bit apply.

namespace {
constexpr int NS     = 4;
constexpr int BATCH  = 512;
constexpr int TLEN   = 32768;      // 2^15
constexpr int NSTATE = 8;
constexpr int P      = 512;        // chunks per batch = threads per block
constexpr int L      = TLEN / P;   // 64 steps per chunk
constexpr int LQ     = L / 4;      // 16 float4 per chunk
constexpr int NMS    = 7;          // Ms[d] = M^(2^d), d=0..6 (M = A^64)
}

#if defined(__has_builtin)
#  if __has_builtin(__builtin_amdgcn_global_load_lds)
#    define USE_GLL 1
#  endif
#endif
#ifndef USE_GLL
#  define USE_GLL 0
#endif

#define WAIT_VM0 do { asm volatile("s_waitcnt vmcnt(0)" ::: "memory"); \
                      __builtin_amdgcn_sched_barrier(0); } while (0)
#define WAIT_LGKM0 do { asm volatile("s_waitcnt lgkmcnt(0)" ::: "memory"); \
                        __builtin_amdgcn_sched_barrier(0); } while (0)
#define RAW_BARRIER do { __builtin_amdgcn_s_barrier(); \
                         __builtin_amdgcn_sched_barrier(0); } while (0)

__device__ __forceinline__ void load_coefs(const float* __restrict__ bc,
                                           const float* __restrict__ ac,
                                           float b0[NS], float b1[NS], float b2[NS],
                                           float a1[NS], float a2[NS]) {
#pragma unroll
  for (int k = 0; k < NS; ++k) {
    b0[k] = bc[3 * k];
    b1[k] = bc[3 * k + 1];
    b2[k] = bc[3 * k + 2];
    a1[k] = ac[2 * k];
    a2[k] = ac[2 * k + 1];
  }
}

// One time-step through the 4-section cascade (matches reference exactly).
__device__ __forceinline__ float step_cascade(float sig,
                                              const float b0[NS], const float b1[NS],
                                              const float b2[NS], const float a1[NS],
                                              const float a2[NS],
                                              float s1[NS], float s2[NS]) {
#pragma unroll
  for (int k = 0; k < NS; ++k) {
    float y = fmaf(b0[k], sig, s1[k]);
    s1[k]   = fmaf(-a1[k], y, fmaf(b1[k], sig, s2[k]));
    s2[k]   = fmaf(-a2[k], y, b2[k] * sig);
    sig = y;
  }
  return sig;
}

#define CO b0, b1, b2, a1, a2

__device__ __forceinline__ void adv4(const float4 u,
                                     const float b0[NS], const float b1[NS],
                                     const float b2[NS], const float a1[NS],
                                     const float a2[NS], float s1[NS], float s2[NS]) {
  (void)step_cascade(u.x, CO, s1, s2);
  (void)step_cascade(u.y, CO, s1, s2);
  (void)step_cascade(u.z, CO, s1, s2);
  (void)step_cascade(u.w, CO, s1, s2);
}

__device__ __forceinline__ float4 out4(const float4 u,
                                       const float b0[NS], const float b1[NS],
                                       const float b2[NS], const float a1[NS],
                                       const float a2[NS], float s1[NS], float s2[NS]) {
  float4 y;
  y.x = step_cascade(u.x, CO, s1, s2);
  y.y = step_cascade(u.y, CO, s1, s2);
  y.z = step_cascade(u.z, CO, s1, s2);
  y.w = step_cascade(u.w, CO, s1, s2);
  return y;
}

// Stage one half-tile (64 chunks x 8 f4 = 8KB): linear LDS dest, per-lane
// pre-swizzled global source (R12/R13-validated). Dense 128B lines.
__device__ __forceinline__ void stage_ht(const float4* __restrict__ gx_w,
                                         float4* R, int lane, int ht) {
#if USE_GLL
#pragma unroll
  for (int j = 0; j < 8; ++j) {
    const int cc = j * 8 + (lane >> 3);
    const int qq = lane & 7;
    const float4* g = gx_w + cc * 16 + ht * 8 + (qq ^ (cc & 7));
    __builtin_amdgcn_global_load_lds(
        (const __attribute__((address_space(1))) void*)g,
        (__attribute__((address_space(3))) void*)&R[j * 64], 16, 0, 0);
  }
#else
#pragma unroll
  for (int j = 0; j < 8; ++j) {
    const int cc = j * 8 + (lane >> 3);
    const int qq = lane & 7;
    R[j * 64 + lane] = gx_w[cc * 16 + ht * 8 + (qq ^ (cc & 7))];
  }
#endif
}

__global__ __launch_bounds__(P) void k_fused(const float* __restrict__ x,
                                             const float* __restrict__ bc,
                                             const float* __restrict__ ac,
                                             float* __restrict__ out) {
  // EXACTLY 64KB static LDS. Wave wv owns f4 [wv*512, +512).
  // During the scan window, wave 0's region holds Msf (7x64) + Bndf (8x8).
  __shared__ float4 arena[4096];
  float* Msf  = reinterpret_cast<float*>(arena);        // floats [0,448)
  float* Bndf = reinterpret_cast<float*>(arena) + 448;  // floats [448,512)

  const int t    = threadIdx.x;
  const int lane = t & 63;
  const int wv   = t >> 6;
  const int swz  = lane & 7;
  float4* __restrict__ R = arena + (wv << 9);

  float b0[NS], b1[NS], b2[NS], a1[NS], a2[NS];
  load_coefs(bc, ac, b0, b1, b2, a1, a2);

  const float4* __restrict__ gx_w = reinterpret_cast<const float4*>(x) +
      (size_t)blockIdx.x * (P * LQ) + ((size_t)wv << 10);
  float4* __restrict__ gy_w = reinterpret_cast<float4*>(out) +
      (size_t)blockIdx.x * (P * LQ) + ((size_t)wv << 10);

  // ---- P1 HT0 staging (HBM latency hides under Ms squarings) ----
  stage_ht(gx_w, R, lane, 0);

  // ---- EVERY wave: Ms[d]=(A^64)^(2^d) in-register via __shfl; KEEP in
  //      registers (LDS write deferred past P1 -- wave 0's region is busy) ----
  float mpow[NMS];
  {
    const int r = lane >> 3, c = lane & 7;
    float p1[NS] = {0.f, 0.f, 0.f, 0.f};
    float p2[NS] = {0.f, 0.f, 0.f, 0.f};
    if (c & 1) p2[c >> 1] = 1.0f; else p1[c >> 1] = 1.0f;
    (void)step_cascade(0.0f, CO, p1, p2);
    float m = (r & 1) ? p2[r >> 1] : p1[r >> 1];  // A element (r,c)
#pragma unroll
    for (int it = 0; it < 12; ++it) {  // A^2..A^4096; M^(2^d) at it = 5+d
      float acc = 0.0f;
#pragma unroll
      for (int k = 0; k < NSTATE; ++k)
        acc = fmaf(__shfl(m, r * 8 + k), __shfl(m, k * 8 + c), acc);
      m = acc;
      if (it >= 5) mpow[it - 5] = m;
    }
  }

  // ---- P1: chunk final state from zero, two half-tiles ----
  float s1[NS] = {0.f, 0.f, 0.f, 0.f};
  float s2[NS] = {0.f, 0.f, 0.f, 0.f};
  WAIT_VM0;
#pragma unroll
  for (int q = 0; q < 8; ++q) adv4(R[lane * 8 + (q ^ swz)], CO, s1, s2);
  WAIT_LGKM0;  // WAR: HT0 reads retired before HT1 overwrites
  stage_ht(gx_w, R, lane, 1);
  WAIT_VM0;
#pragma unroll
  for (int q = 0; q < 8; ++q) adv4(R[lane * 8 + (q ^ swz)], CO, s1, s2);

  float w[NSTATE];
#pragma unroll
  for (int k = 0; k < NS; ++k) { w[2 * k] = s1[k]; w[2 * k + 1] = s2[k]; }

  // ---- barrier #1: all P1 arena reads done; arena reusable ----
  WAIT_LGKM0;
  RAW_BARRIER;

  // waves 1..7: prefetch P4 HT0 now (regions free; loads fly across the scan)
  if (wv != 0) stage_ht(gx_w, R, lane, 0);
  // all waves write Msf redundantly (identical values -> benign race)
#pragma unroll
  for (int d = 0; d < NMS; ++d) Msf[d * 64 + lane] = mpow[d];
  WAIT_LGKM0;  // own-wave Msf writes visible to own-wave reads

  // ---- in-wave Kogge-Stone levels 0..5 (shfl + uniform Msf reads) ----
#pragma unroll
  for (int d = 0; d < 6; ++d) {
    const int off = 1 << d;
    const int src = (lane >= off) ? (lane - off) : lane;
    float prev[NSTATE];
#pragma unroll
    for (int r = 0; r < NSTATE; ++r) prev[r] = __shfl(w[r], src);
    if (lane >= off) {
#pragma unroll
      for (int r = 0; r < NSTATE; ++r) {
        float acc = w[r];
#pragma unroll
        for (int k = 0; k < NSTATE; ++k)
          acc = fmaf(Msf[d * 64 + r * 8 + k], prev[k], acc);  // broadcast
        w[r] = acc;
      }
    }
  }

  // ---- barrier #2: Bnd exchange (lgkm-only drain; gll stays in flight) ----
  if (lane == 63) {
#pragma unroll
    for (int r = 0; r < NSTATE; ++r) Bndf[wv * 8 + r] = w[r];
  }
  WAIT_LGKM0;
  RAW_BARRIER;

  // ---- cross-wave prefix P_wv: fold Bnd[0..wv-1] through M^64 = Msf[6] ----
  float Pv[NSTATE] = {0.f, 0.f, 0.f, 0.f, 0.f, 0.f, 0.f, 0.f};
  for (int j = 0; j < wv; ++j) {  // wave-uniform trip count
    float np[NSTATE];
#pragma unroll
    for (int r = 0; r < NSTATE; ++r) {
      float acc = Bndf[j * 8 + r];
#pragma unroll
      for (int k = 0; k < NSTATE; ++k)
        acc = fmaf(Msf[6 * 64 + r * 8 + k], Pv[k], acc);
      np[r] = acc;
    }
#pragma unroll
    for (int r = 0; r < NSTATE; ++r) Pv[r] = np[r];
  }

  // ---- z = M^lane * P (binary bits); s_init = u_excl_local + z ----
  float z[NSTATE];
#pragma unroll
  for (int r = 0; r < NSTATE; ++r) z[r] = Pv[r];
#pragma unroll
  for (int b = 0; b < 6; ++b) {
    float zb[NSTATE];
#pragma unroll
    for (int r = 0; r < NSTATE; ++r) {
      float acc = 0.0f;
#pragma unroll
      for (int k = 0; k < NSTATE; ++k)
        acc = fmaf(Msf[b * 64 + r * 8 + k], z[k], acc);
      zb[r] = acc;
    }
    const bool bit = (lane >> b) & 1;
#pragma unroll
    for (int r = 0; r < NSTATE; ++r) z[r] = bit ? zb[r] : z[r];
  }
  {
    const int esrc = lane ? lane - 1 : 0;
#pragma unroll
    for (int k = 0; k < NS; ++k) {
      const float ue0 = __shfl(w[2 * k], esrc);
      const float ue1 = __shfl(w[2 * k + 1], esrc);
      s1[k] = (lane ? ue0 : 0.0f) + z[2 * k];
      s2[k] = (lane ? ue1 : 0.0f) + z[2 * k + 1];
    }
  }

  // ---- barrier #3: all Msf/Bnd reads done; wave 0's region reusable ----
  WAIT_LGKM0;
  RAW_BARRIER;
  if (wv == 0) stage_ht(gx_w, R, lane, 0);  // deferred HT0 stage for wave 0

  // ---- P4: replay from exact init (R13/R15 strict sequence) ----
#pragma unroll
  for (int ht = 0; ht < 2; ++ht) {
    if (ht == 1) stage_ht(gx_w, R, lane, 1);  // HT0 already staged
    WAIT_VM0;
#pragma unroll
    for (int q = 0; q < 8; ++q) {
      const int s = lane * 8 + (q ^ swz);
      R[s] = out4(R[s], CO, s1, s2);  // in-place: own slots only
    }
    WAIT_LGKM0;  // in-place writes committed before transpose-out reads
#pragma unroll
    for (int j = 0; j < 8; ++j) {
      const int cc = j * 8 + (lane >> 3);
      const int qq = lane & 7;
      const float4 v = R[j * 64 + lane];
      gy_w[cc * 16 + ht * 8 + (qq ^ (cc & 7))] = v;  // dense 128B lines
    }
    if (ht == 0) WAIT_LGKM0;  // WAR: store-side ds_reads done before HT1 staging
  }
}

extern "C" void kernel_launch(void* const* d_in, const int* in_sizes, int n_in,
                              void* d_out, int out_size, void* d_ws, size_t ws_size,
                              hipStream_t stream) {
  const float* x  = (const float*)d_in[0];  // (B, T, 1)
  const float* bc = (const float*)d_in[1];  // (NS, 3)
  const float* ac = (const float*)d_in[2];  // (NS, 2)
  float* out = (float*)d_out;               // (B, T, 1)

  k_fused<<<BATCH, P, 0, stream>>>(x, bc, ac, out);
}

// Round 17
// 107.398 us; speedup vs baseline: 1.0727x; 1.0727x over previous
//
#include <hip/hip_runtime.h>

// Fully-fused cascaded-biquad IIR (DF2T) via linear state-space chunking.
// R17 = R13 champion skeleton + three deltas:
//   1) P1 staged as quarter-tiles (4KB) with 2-deep counted-vmcnt pipeline
//   2) shfl-scan (R14/R15/R16-verified math) with Msf+Bnd aliased into the
//      first 2KB of wave 0's arena region -> total LDS EXACTLY 64KiB
//      (65536 -> 2 blocks/CU; 67584 -> 1 block/CU, R13/R15 triangulation).
//      Squarings: all waves, stored to LDS immediately (R15 codegen, no
//      register retention -- R16's spill bomb).
//   3) P4 HT0 prefetch for waves 1..7 before the scan; raw s_barriers keep
//      the gll loads in flight. Wave 0 stages after barrier #3.
// P4 compute/store = R13 verbatim (strict WAIT_VM0 sequence, WRITE=66MB).

namespace {
constexpr int NS     = 4;
constexpr int BATCH  = 512;
constexpr int TLEN   = 32768;      // 2^15
constexpr int NSTATE = 8;
constexpr int P      = 512;        // chunks per batch = threads per block
constexpr int L      = TLEN / P;   // 64 steps per chunk
constexpr int LQ     = L / 4;      // 16 float4 per chunk
constexpr int NMS    = 7;          // Msf[d] = M^(2^d), d=0..6 (M = A^64)
}

#if defined(__has_builtin)
#  if __has_builtin(__builtin_amdgcn_global_load_lds)
#    define USE_GLL 1
#  endif
#endif
#ifndef USE_GLL
#  define USE_GLL 0
#endif

#define WAIT_VM0 do { asm volatile("s_waitcnt vmcnt(0)" ::: "memory"); \
                      __builtin_amdgcn_sched_barrier(0); } while (0)
#define WAIT_VM4 do { asm volatile("s_waitcnt vmcnt(4)" ::: "memory"); \
                      __builtin_amdgcn_sched_barrier(0); } while (0)
#define WAIT_LGKM0 do { asm volatile("s_waitcnt lgkmcnt(0)" ::: "memory"); \
                        __builtin_amdgcn_sched_barrier(0); } while (0)
#define RAW_BARRIER do { __builtin_amdgcn_s_barrier(); \
                         __builtin_amdgcn_sched_barrier(0); } while (0)

__device__ __forceinline__ void load_coefs(const float* __restrict__ bc,
                                           const float* __restrict__ ac,
                                           float b0[NS], float b1[NS], float b2[NS],
                                           float a1[NS], float a2[NS]) {
#pragma unroll
  for (int k = 0; k < NS; ++k) {
    b0[k] = bc[3 * k];
    b1[k] = bc[3 * k + 1];
    b2[k] = bc[3 * k + 2];
    a1[k] = ac[2 * k];
    a2[k] = ac[2 * k + 1];
  }
}

// One time-step through the 4-section cascade (matches reference exactly).
__device__ __forceinline__ float step_cascade(float sig,
                                              const float b0[NS], const float b1[NS],
                                              const float b2[NS], const float a1[NS],
                                              const float a2[NS],
                                              float s1[NS], float s2[NS]) {
#pragma unroll
  for (int k = 0; k < NS; ++k) {
    float y = fmaf(b0[k], sig, s1[k]);
    s1[k]   = fmaf(-a1[k], y, fmaf(b1[k], sig, s2[k]));
    s2[k]   = fmaf(-a2[k], y, b2[k] * sig);
    sig = y;
  }
  return sig;
}

#define CO b0, b1, b2, a1, a2

__device__ __forceinline__ void adv4(const float4 u,
                                     const float b0[NS], const float b1[NS],
                                     const float b2[NS], const float a1[NS],
                                     const float a2[NS], float s1[NS], float s2[NS]) {
  (void)step_cascade(u.x, CO, s1, s2);
  (void)step_cascade(u.y, CO, s1, s2);
  (void)step_cascade(u.z, CO, s1, s2);
  (void)step_cascade(u.w, CO, s1, s2);
}

__device__ __forceinline__ float4 out4(const float4 u,
                                       const float b0[NS], const float b1[NS],
                                       const float b2[NS], const float a1[NS],
                                       const float a2[NS], float s1[NS], float s2[NS]) {
  float4 y;
  y.x = step_cascade(u.x, CO, s1, s2);
  y.y = step_cascade(u.y, CO, s1, s2);
  y.z = step_cascade(u.z, CO, s1, s2);
  y.w = step_cascade(u.w, CO, s1, s2);
  return y;
}

// ---- P1 quarter-tile staging: 4KB = 64 chunks x 4 f4 into buffer A/B.
// Swizzle: slot(c,q) = c*4 + (q ^ ((c>>1)&3))  -> ~2 lanes/bank on reads.
__device__ __forceinline__ void stage_qt(const float4* __restrict__ gx_w,
                                         float4* R, int lane, int qt, int buf) {
  float4* D = R + buf * 256;
#if USE_GLL
#pragma unroll
  for (int j = 0; j < 4; ++j) {
    const int cc = j * 16 + (lane >> 2);
    const int qq = lane & 3;
    const float4* g = gx_w + cc * 16 + qt * 4 + (qq ^ ((cc >> 1) & 3));
    __builtin_amdgcn_global_load_lds(
        (const __attribute__((address_space(1))) void*)g,
        (__attribute__((address_space(3))) void*)&D[j * 64], 16, 0, 0);
  }
#else
#pragma unroll
  for (int j = 0; j < 4; ++j) {
    const int cc = j * 16 + (lane >> 2);
    const int qq = lane & 3;
    D[j * 64 + lane] = gx_w[cc * 16 + qt * 4 + (qq ^ ((cc >> 1) & 3))];
  }
#endif
}

// ---- P4 half-tile staging (R13 verbatim): 8KB, slot(c,q)=c*8+(q^(c&7)).
__device__ __forceinline__ void stage_ht(const float4* __restrict__ gx_w,
                                         float4* R, int lane, int ht) {
#if USE_GLL
#pragma unroll
  for (int j = 0; j < 8; ++j) {
    const int cc = j * 8 + (lane >> 3);
    const int qq = lane & 7;
    const float4* g = gx_w + cc * 16 + ht * 8 + (qq ^ (cc & 7));
    __builtin_amdgcn_global_load_lds(
        (const __attribute__((address_space(1))) void*)g,
        (__attribute__((address_space(3))) void*)&R[j * 64], 16, 0, 0);
  }
#else
#pragma unroll
  for (int j = 0; j < 8; ++j) {
    const int cc = j * 8 + (lane >> 3);
    const int qq = lane & 7;
    R[j * 64 + lane] = gx_w[cc * 16 + ht * 8 + (qq ^ (cc & 7))];
  }
#endif
}

__global__ __launch_bounds__(P) void k_fused(const float* __restrict__ x,
                                             const float* __restrict__ bc,
                                             const float* __restrict__ ac,
                                             float* __restrict__ out) {
  // EXACTLY 64KB static LDS. Wave wv owns f4 [wv*512, +512).
  // Scan window: wave 0's first 2KB holds Msf (7x64) + Bndf (8x8).
  __shared__ float4 arena[4096];
  float* Msf  = reinterpret_cast<float*>(arena);        // floats [0,448)
  float* Bndf = reinterpret_cast<float*>(arena) + 448;  // floats [448,512)

  const int t    = threadIdx.x;
  const int lane = t & 63;
  const int wv   = t >> 6;
  const int swz  = lane & 7;
  const int qswz = (lane >> 1) & 3;
  float4* __restrict__ R = arena + (wv << 9);

  float b0[NS], b1[NS], b2[NS], a1[NS], a2[NS];
  load_coefs(bc, ac, b0, b1, b2, a1, a2);

  const float4* __restrict__ gx_w = reinterpret_cast<const float4*>(x) +
      (size_t)blockIdx.x * (P * LQ) + ((size_t)wv << 10);
  float4* __restrict__ gy_w = reinterpret_cast<float4*>(out) +
      (size_t)blockIdx.x * (P * LQ) + ((size_t)wv << 10);

  // ================= P1: quarter-tile 2-deep pipeline =================
  stage_qt(gx_w, R, lane, 0, 0);  // QT0 -> A
  stage_qt(gx_w, R, lane, 1, 1);  // QT1 -> B

  float s1[NS] = {0.f, 0.f, 0.f, 0.f};
  float s2[NS] = {0.f, 0.f, 0.f, 0.f};

  WAIT_VM4;  // QT0 landed (QT1 still flying)
#pragma unroll
  for (int q = 0; q < 4; ++q) adv4(R[lane * 4 + (q ^ qswz)], CO, s1, s2);
  WAIT_LGKM0;  // A reads retired
  stage_qt(gx_w, R, lane, 2, 0);  // QT2 -> A
  WAIT_VM4;  // QT1 landed
#pragma unroll
  for (int q = 0; q < 4; ++q) adv4(R[256 + lane * 4 + (q ^ qswz)], CO, s1, s2);
  WAIT_LGKM0;  // B reads retired
  stage_qt(gx_w, R, lane, 3, 1);  // QT3 -> B
  WAIT_VM4;  // QT2 landed
#pragma unroll
  for (int q = 0; q < 4; ++q) adv4(R[lane * 4 + (q ^ qswz)], CO, s1, s2);
  WAIT_VM0;  // QT3 landed
#pragma unroll
  for (int q = 0; q < 4; ++q) adv4(R[256 + lane * 4 + (q ^ qswz)], CO, s1, s2);

  float w[NSTATE];
#pragma unroll
  for (int k = 0; k < NS; ++k) { w[2 * k] = s1[k]; w[2 * k + 1] = s2[k]; }

  WAIT_LGKM0;  // all P1 reads retired
  RAW_BARRIER;  // ---- barrier #1: arena reusable ----

  // waves 1..7: prefetch P4 HT0 (their regions free; flies across the scan)
  if (wv != 0) stage_ht(gx_w, R, lane, 0);

  // ---- all waves: Ms squarings, stored IMMEDIATELY (R15 codegen) ----
  {
    const int r = lane >> 3, c = lane & 7;
    float p1[NS] = {0.f, 0.f, 0.f, 0.f};
    float p2[NS] = {0.f, 0.f, 0.f, 0.f};
    if (c & 1) p2[c >> 1] = 1.0f; else p1[c >> 1] = 1.0f;
    (void)step_cascade(0.0f, CO, p1, p2);
    float m = (r & 1) ? p2[r >> 1] : p1[r >> 1];  // A element (r,c)
#pragma unroll
    for (int it = 0; it < 12; ++it) {  // A^2..A^4096; M^(2^d) at it = 5+d
      float acc = 0.0f;
#pragma unroll
      for (int k = 0; k < NSTATE; ++k)
        acc = fmaf(__shfl(m, r * 8 + k), __shfl(m, k * 8 + c), acc);
      m = acc;
      if (it >= 5) Msf[(it - 5) * 64 + lane] = m;  // benign identical-value race
    }
  }
  WAIT_LGKM0;  // own-wave Msf writes visible to own-wave reads

  // ---- in-wave Kogge-Stone levels 0..5 (shfl + uniform Msf reads) ----
#pragma unroll
  for (int d = 0; d < 6; ++d) {
    const int off = 1 << d;
    const int src = (lane >= off) ? (lane - off) : lane;
    float prev[NSTATE];
#pragma unroll
    for (int r = 0; r < NSTATE; ++r) prev[r] = __shfl(w[r], src);
    if (lane >= off) {
#pragma unroll
      for (int r = 0; r < NSTATE; ++r) {
        float acc = w[r];
#pragma unroll
        for (int k = 0; k < NSTATE; ++k)
          acc = fmaf(Msf[d * 64 + r * 8 + k], prev[k], acc);  // broadcast
        w[r] = acc;
      }
    }
  }

  // ---- barrier #2: Bnd exchange (raw: gll loads stay in flight) ----
  if (lane == 63) {
#pragma unroll
    for (int r = 0; r < NSTATE; ++r) Bndf[wv * 8 + r] = w[r];
  }
  WAIT_LGKM0;
  RAW_BARRIER;

  // ---- cross-wave prefix: fold Bnd[0..wv-1] through M^64 = Msf[6] ----
  float Pv[NSTATE] = {0.f, 0.f, 0.f, 0.f, 0.f, 0.f, 0.f, 0.f};
  for (int j = 0; j < wv; ++j) {  // wave-uniform trip count
    float np[NSTATE];
#pragma unroll
    for (int r = 0; r < NSTATE; ++r) {
      float acc = Bndf[j * 8 + r];
#pragma unroll
      for (int k = 0; k < NSTATE; ++k)
        acc = fmaf(Msf[6 * 64 + r * 8 + k], Pv[k], acc);
      np[r] = acc;
    }
#pragma unroll
    for (int r = 0; r < NSTATE; ++r) Pv[r] = np[r];
  }

  // ---- z = M^lane * P (binary bits); s_init = u_excl_local + z ----
  float z[NSTATE];
#pragma unroll
  for (int r = 0; r < NSTATE; ++r) z[r] = Pv[r];
#pragma unroll
  for (int b = 0; b < 6; ++b) {
    float zb[NSTATE];
#pragma unroll
    for (int r = 0; r < NSTATE; ++r) {
      float acc = 0.0f;
#pragma unroll
      for (int k = 0; k < NSTATE; ++k)
        acc = fmaf(Msf[b * 64 + r * 8 + k], z[k], acc);
      zb[r] = acc;
    }
    const bool bit = (lane >> b) & 1;
#pragma unroll
    for (int r = 0; r < NSTATE; ++r) z[r] = bit ? zb[r] : z[r];
  }
  {
    const int esrc = lane ? lane - 1 : 0;
#pragma unroll
    for (int k = 0; k < NS; ++k) {
      const float ue0 = __shfl(w[2 * k], esrc);
      const float ue1 = __shfl(w[2 * k + 1], esrc);
      s1[k] = (lane ? ue0 : 0.0f) + z[2 * k];
      s2[k] = (lane ? ue1 : 0.0f) + z[2 * k + 1];
    }
  }

  // ---- barrier #3: Msf/Bnd reads done; wave 0's region reusable ----
  WAIT_LGKM0;
  RAW_BARRIER;
  if (wv == 0) stage_ht(gx_w, R, lane, 0);  // wave 0 catch-up stage

  // ================= P4: replay (R13 strict sequence) =================
#pragma unroll
  for (int ht = 0; ht < 2; ++ht) {
    if (ht == 1) stage_ht(gx_w, R, lane, 1);  // HT0 already staged
    WAIT_VM0;
#pragma unroll
    for (int q = 0; q < 8; ++q) {
      const int s = lane * 8 + (q ^ swz);
      R[s] = out4(R[s], CO, s1, s2);  // in-place: own slots only
    }
    WAIT_LGKM0;  // in-place writes committed before transpose-out reads
#pragma unroll
    for (int j = 0; j < 8; ++j) {
      const int cc = j * 8 + (lane >> 3);
      const int qq = lane & 7;
      const float4 v = R[j * 64 + lane];
      gy_w[cc * 16 + ht * 8 + (qq ^ (cc & 7))] = v;  // dense 128B lines
    }
    if (ht == 0) WAIT_LGKM0;  // WAR: store-side ds_reads done before HT1 staging
  }
}

extern "C" void kernel_launch(void* const* d_in, const int* in_sizes, int n_in,
                              void* d_out, int out_size, void* d_ws, size_t ws_size,
                              hipStream_t stream) {
  const float* x  = (const float*)d_in[0];  // (B, T, 1)
  const float* bc = (const float*)d_in[1];  // (NS, 3)
  const float* ac = (const float*)d_in[2];  // (NS, 2)
  float* out = (float*)d_out;               // (B, T, 1)

  k_fused<<<BATCH, P, 0, stream>>>(x, bc, ac, out);
}

// Round 18
// 41.471 us; speedup vs baseline: 2.7779x; 2.5897x over previous
//
#include <hip/hip_runtime.h>

// Fully-fused cascaded-biquad IIR (DF2T) via linear state-space chunking.
// R18 = R13 champion (41.5us, VGPR 52, FETCH/WRITE 66MB) + two surgical
// deltas that preserve its codegen shape:
//   1) scan levels 0..5 in-wave via __shfl (same Msf reads; prev[] comes
//      from shfl instead of Wf) -> barriers 21 -> 10. Levels 6..8 and the
//      exclusive shift keep R13's exact Wf-exchange code.
//   2) Wf spans only waves 0..2's arena regions (floats < 5184), so waves
//      3..7 prefetch their P4 HT0 BEFORE the scan (disjoint regions); the
//      shfl-scan covers part of the load latency. Waves 0..2 stage after
//      the final barrier exactly as in R13.
// Everything else is R13 verbatim: 64KB static LDS (the 2-blocks/CU cliff
// is at exactly 65536: 2x65536 = 128KB usable/CU), wave-0 mpow[9] squaring
// hidden under P1 HT0 load, strict WAIT_VM0 P4 sequence.

namespace {
constexpr int NS     = 4;
constexpr int BATCH  = 512;
constexpr int TLEN   = 32768;      // 2^15
constexpr int NSTATE = 8;
constexpr int P      = 512;        // chunks per batch = threads per block
constexpr int L      = TLEN / P;   // 64 steps per chunk
constexpr int LQ     = L / 4;      // 16 float4 per chunk
constexpr int LOG2P  = 9;
constexpr int LOG2L  = 6;
constexpr int NSQ    = LOG2L + LOG2P - 1;  // 14 squaring iterations
}

#if defined(__has_builtin)
#  if __has_builtin(__builtin_amdgcn_global_load_lds)
#    define USE_GLL 1
#  endif
#endif
#ifndef USE_GLL
#  define USE_GLL 0
#endif

#define WAIT_VM0 do { asm volatile("s_waitcnt vmcnt(0)" ::: "memory"); \
                      __builtin_amdgcn_sched_barrier(0); } while (0)
#define WAIT_LGKM0 do { asm volatile("s_waitcnt lgkmcnt(0)" ::: "memory"); \
                        __builtin_amdgcn_sched_barrier(0); } while (0)

__device__ __forceinline__ void load_coefs(const float* __restrict__ bc,
                                           const float* __restrict__ ac,
                                           float b0[NS], float b1[NS], float b2[NS],
                                           float a1[NS], float a2[NS]) {
#pragma unroll
  for (int k = 0; k < NS; ++k) {
    b0[k] = bc[3 * k];
    b1[k] = bc[3 * k + 1];
    b2[k] = bc[3 * k + 2];
    a1[k] = ac[2 * k];
    a2[k] = ac[2 * k + 1];
  }
}

// One time-step through the 4-section cascade (matches reference exactly).
__device__ __forceinline__ float step_cascade(float sig,
                                              const float b0[NS], const float b1[NS],
                                              const float b2[NS], const float a1[NS],
                                              const float a2[NS],
                                              float s1[NS], float s2[NS]) {
#pragma unroll
  for (int k = 0; k < NS; ++k) {
    float y = fmaf(b0[k], sig, s1[k]);
    s1[k]   = fmaf(-a1[k], y, fmaf(b1[k], sig, s2[k]));
    s2[k]   = fmaf(-a2[k], y, b2[k] * sig);
    sig = y;
  }
  return sig;
}

#define CO b0, b1, b2, a1, a2

__device__ __forceinline__ void adv4(const float4 u,
                                     const float b0[NS], const float b1[NS],
                                     const float b2[NS], const float a1[NS],
                                     const float a2[NS], float s1[NS], float s2[NS]) {
  (void)step_cascade(u.x, CO, s1, s2);
  (void)step_cascade(u.y, CO, s1, s2);
  (void)step_cascade(u.z, CO, s1, s2);
  (void)step_cascade(u.w, CO, s1, s2);
}

__device__ __forceinline__ float4 out4(const float4 u,
                                       const float b0[NS], const float b1[NS],
                                       const float b2[NS], const float a1[NS],
                                       const float a2[NS], float s1[NS], float s2[NS]) {
  float4 y;
  y.x = step_cascade(u.x, CO, s1, s2);
  y.y = step_cascade(u.y, CO, s1, s2);
  y.z = step_cascade(u.z, CO, s1, s2);
  y.w = step_cascade(u.w, CO, s1, s2);
  return y;
}

// Stage one half-tile (64 chunks x 8 f4 = 8KB): linear LDS dest, per-lane
// pre-swizzled global source (R12/R13-validated). Dense 128B lines.
__device__ __forceinline__ void stage_ht(const float4* __restrict__ gx_w,
                                         float4* R, int lane, int ht) {
#if USE_GLL
#pragma unroll
  for (int j = 0; j < 8; ++j) {
    const int cc = j * 8 + (lane >> 3);
    const int qq = lane & 7;
    const float4* g = gx_w + cc * 16 + ht * 8 + (qq ^ (cc & 7));
    __builtin_amdgcn_global_load_lds(
        (const __attribute__((address_space(1))) void*)g,
        (__attribute__((address_space(3))) void*)&R[j * 64], 16, 0, 0);
  }
#else
#pragma unroll
  for (int j = 0; j < 8; ++j) {
    const int cc = j * 8 + (lane >> 3);
    const int qq = lane & 7;
    R[j * 64 + lane] = gx_w[cc * 16 + ht * 8 + (qq ^ (cc & 7))];
  }
#endif
}

__global__ __launch_bounds__(P) void k_fused(const float* __restrict__ x,
                                             const float* __restrict__ bc,
                                             const float* __restrict__ ac,
                                             float* __restrict__ out) {
  // 64 KiB arena. P1/P4: wave wv owns f4 [wv*512, wv*512+512).
  // Scan: Msf = floats [0,576), Wf = floats [576,5184) -- covers only
  // waves 0..2's regions; waves 3..7 (f4 >= 1536 = float 6144) are free.
  __shared__ float4 arena[4096];
  float* Msf = reinterpret_cast<float*>(arena);
  float* Wf  = reinterpret_cast<float*>(arena) + 576;

  const int t    = threadIdx.x;
  const int lane = t & 63;
  const int wv   = t >> 6;
  const int swz  = lane & 7;
  float4* __restrict__ R = arena + (wv << 9);

  float b0[NS], b1[NS], b2[NS], a1[NS], a2[NS];
  load_coefs(bc, ac, b0, b1, b2, a1, a2);

  const float4* __restrict__ gx_w = reinterpret_cast<const float4*>(x) +
      (size_t)blockIdx.x * (P * LQ) + ((size_t)wv << 10);
  float4* __restrict__ gy_w = reinterpret_cast<float4*>(out) +
      (size_t)blockIdx.x * (P * LQ) + ((size_t)wv << 10);

  // ---- P1 HT0 staging (HBM latency hides under Ms squarings) ----
  stage_ht(gx_w, R, lane, 0);

  // ---- Ms squarings in-register (wave 0 only), stored AFTER P1 barrier ----
  float mpow[9];
#pragma unroll
  for (int i = 0; i < 9; ++i) mpow[i] = 0.0f;
  if (t < 64) {
    const int r = lane >> 3, c = lane & 7;
    float p1[NS] = {0.f, 0.f, 0.f, 0.f};
    float p2[NS] = {0.f, 0.f, 0.f, 0.f};
    if (c & 1) p2[c >> 1] = 1.0f; else p1[c >> 1] = 1.0f;
    (void)step_cascade(0.0f, CO, p1, p2);
    float m = (r & 1) ? p2[r >> 1] : p1[r >> 1];  // A element (r,c)
#pragma unroll
    for (int it = 0; it < NSQ; ++it) {
      float acc = 0.0f;
#pragma unroll
      for (int k = 0; k < NSTATE; ++k)
        acc = fmaf(__shfl(m, r * 8 + k), __shfl(m, k * 8 + c), acc);
      m = acc;
      if (it >= LOG2L - 1) mpow[it - (LOG2L - 1)] = m;
    }
  }

  // ---- P1: compute chunk state from zero, half-tile at a time ----
  float s1[NS] = {0.f, 0.f, 0.f, 0.f};
  float s2[NS] = {0.f, 0.f, 0.f, 0.f};
  WAIT_VM0;
#pragma unroll
  for (int q = 0; q < 8; ++q) adv4(R[lane * 8 + (q ^ swz)], CO, s1, s2);
  WAIT_LGKM0;  // WAR: ds_reads done before HT1 overwrites the region
  stage_ht(gx_w, R, lane, 1);
  WAIT_VM0;
#pragma unroll
  for (int q = 0; q < 8; ++q) adv4(R[lane * 8 + (q ^ swz)], CO, s1, s2);

  float w[NSTATE];
#pragma unroll
  for (int k = 0; k < NS; ++k) { w[2 * k] = s1[k]; w[2 * k + 1] = s2[k]; }

  __syncthreads();  // #1: all P1 LDS traffic done; arena repurposed
  if (t < 64) {
#pragma unroll
    for (int d = 0; d < LOG2P; ++d) Msf[d * 64 + t] = mpow[d];
  }
  // waves 3..7: regions disjoint from Msf/Wf -> prefetch P4 HT0 now;
  // the shfl-scan below covers part of the load latency.
  if (wv >= 3) stage_ht(gx_w, R, lane, 0);
  __syncthreads();  // #2: Msf visible to all waves

  // ---- scan levels 0..5: in-wave Kogge-Stone via __shfl (no barriers) ----
#pragma unroll
  for (int d = 0; d < 6; ++d) {
    const int off = 1 << d;
    const int src = (lane >= off) ? (lane - off) : lane;
    float prev[NSTATE];
#pragma unroll
    for (int r = 0; r < NSTATE; ++r) prev[r] = __shfl(w[r], src);
    if (lane >= off) {
#pragma unroll
      for (int r = 0; r < NSTATE; ++r) {
        float acc = w[r];
#pragma unroll
        for (int k = 0; k < NSTATE; ++k)
          acc = fmaf(Msf[d * 64 + r * 8 + k], prev[k], acc);  // broadcast
        w[r] = acc;
      }
    }
  }

  // ---- scan levels 6..8: R13's Wf-exchange, verbatim ----
  for (int d = 6; d < LOG2P; ++d) {
#pragma unroll
    for (int r = 0; r < NSTATE; ++r) Wf[t * 9 + r] = w[r];
    __syncthreads();
    if (t >= (1 << d)) {
      const int src = (t - (1 << d)) * 9;
      float prev[NSTATE];
#pragma unroll
      for (int r = 0; r < NSTATE; ++r) prev[r] = Wf[src + r];
#pragma unroll
      for (int r = 0; r < NSTATE; ++r) {
        float acc = w[r];
#pragma unroll
        for (int k = 0; k < NSTATE; ++k)
          acc = fmaf(Msf[d * 64 + r * 8 + k], prev[k], acc);  // broadcast
        w[r] = acc;
      }
    }
    __syncthreads();
  }

  // ---- exclusive shift -> s_init in registers (R13 verbatim) ----
#pragma unroll
  for (int r = 0; r < NSTATE; ++r) Wf[t * 9 + r] = w[r];
  __syncthreads();
  {
    const int src = (t == 0 ? 0 : t - 1) * 9;
#pragma unroll
    for (int k = 0; k < NS; ++k) {
      s1[k] = (t == 0) ? 0.0f : Wf[src + 2 * k];
      s2[k] = (t == 0) ? 0.0f : Wf[src + 2 * k + 1];
    }
  }
  __syncthreads();  // scan reads done before P4 staging overwrites arena

  // ---- P4: replay from exact init (R13 strict sequence; HT0 hoisted) ----
  if (wv < 3) stage_ht(gx_w, R, lane, 0);  // 3..7 already staged pre-scan
#pragma unroll
  for (int ht = 0; ht < 2; ++ht) {
    if (ht == 1) stage_ht(gx_w, R, lane, 1);
    WAIT_VM0;
#pragma unroll
    for (int q = 0; q < 8; ++q) {
      const int s = lane * 8 + (q ^ swz);
      R[s] = out4(R[s], CO, s1, s2);  // in-place: own slots only
    }
    WAIT_LGKM0;  // in-place writes committed before transpose-out reads
#pragma unroll
    for (int j = 0; j < 8; ++j) {
      const int cc = j * 8 + (lane >> 3);
      const int qq = lane & 7;
      const float4 v = R[j * 64 + lane];
      gy_w[cc * 16 + ht * 8 + (qq ^ (cc & 7))] = v;  // dense 128B lines
    }
    if (ht == 0) WAIT_LGKM0;  // WAR: store-side ds_reads done before HT1 staging
  }
}

extern "C" void kernel_launch(void* const* d_in, const int* in_sizes, int n_in,
                              void* d_out, int out_size, void* d_ws, size_t ws_size,
                              hipStream_t stream) {
  const float* x  = (const float*)d_in[0];  // (B, T, 1)
  const float* bc = (const float*)d_in[1];  // (NS, 3)
  const float* ac = (const float*)d_in[2];  // (NS, 2)
  float* out = (float*)d_out;               // (B, T, 1)

  k_fused<<<BATCH, P, 0, stream>>>(x, bc, ac, out);
}